// Round 2
// baseline (2832.206 us; speedup 1.0000x reference)
//
#include <hip/hip_runtime.h>
#include <hip/hip_bf16.h>
#include <math.h>

// ---- problem constants ----
#define BB 8
#define TT 90
#define HH 290
#define WWI 180
#define PSZ 10
#define NHPc 29
#define NWPc 18
#define NPc 522
#define PDc 100
#define NVc 94
#define KKc 24
#define LLc 2160
#define LPc 2176          // padded L (multiple of 32/64)
#define DDc 256
#define NHEADc 8
#define DHc 32
#define NLc 6
#define DFFc 1024
#define MTOT (BB*LLc)     // 17280

using f32x4 = __attribute__((ext_vector_type(4))) float;
using s16x8 = __attribute__((ext_vector_type(8))) short;
using s16x4 = __attribute__((ext_vector_type(4))) short;

__device__ __forceinline__ short f2bf(float f) {
  union { __hip_bfloat16 h; short s; } u;
  u.h = __float2bfloat16(f);
  return u.s;
}

// ---------------- fp32 -> bf16 weight conversion ----------------
__global__ void cvt_bf16_kernel(const float* __restrict__ src, short* __restrict__ dst, int n) {
  int i = blockIdx.x * 256 + threadIdx.x;
  if (i < n) dst[i] = f2bf(src[i]);
}

// ---------------- sinusoidal PE table (fp32) ----------------
__global__ void pe_kernel(float* __restrict__ pe) {
  int idx = blockIdx.x * 256 + threadIdx.x;
  if (idx >= TT * 128) return;
  int t = idx / 128, i = idx % 128;
  float div = expf((2.0f * i) * (-9.210340371976184f / 256.0f)); // -ln(10000)/256
  float ang = (float)t * div;
  pe[t * DDc + 2 * i]     = sinf(ang);
  pe[t * DDc + 2 * i + 1] = cosf(ang);
}

// ---------------- visible-token ordering: p_idx[b*L + t*K + j] = v ----------------
// one wave per (b,t); ballot prefix gives stable ascending-v order.
// patch_mask dtype is numpy bool (1 byte) -- with a runtime fallback to int32.
__global__ void order_kernel(const unsigned char* __restrict__ pm8,
                             const int* __restrict__ vidx, int* __restrict__ pidx) {
  int gw = (blockIdx.x * blockDim.x + threadIdx.x) >> 6;
  int lane = threadIdx.x & 63;
  if (gw >= BB * TT) return;
  size_t base = (size_t)gw * NPc;  // gw = b*TT + t
  int v0 = lane, v1 = 64 + lane;
  bool vis0 = (pm8[base + vidx[v0]] == 0);
  bool vis1 = (v1 < NVc) && (pm8[base + vidx[v1]] == 0);
  unsigned long long b0 = __ballot(vis0), b1 = __ballot(vis1);
  if (__popcll(b0) + __popcll(b1) != KKc) {   // mask was stored as int32
    const int* pm32 = (const int*)pm8;
    vis0 = (pm32[base + vidx[v0]] == 0);
    vis1 = (v1 < NVc) && (pm32[base + vidx[v1]] == 0);
    b0 = __ballot(vis0); b1 = __ballot(vis1);
  }
  int* outp = pidx + gw * KKc;   // b*L + t*K == gw*K
  unsigned long long lt = (1ull << lane) - 1ull;
  if (vis0) outp[__popcll(b0 & lt)] = v0;
  if (vis1) outp[__popcll(b0) + __popcll(b1 & lt)] = v1;
}

// ---------------- patch gather + embed + pos enc ----------------
// 4 tokens per block; stage 4x100 pixels in LDS; thread d computes channel d.
__global__ __launch_bounds__(256) void embed_kernel(
    const float* __restrict__ ximg, const int* __restrict__ vidx,
    const int* __restrict__ pidx, const float* __restrict__ pew,
    const float* __restrict__ peb, const float* __restrict__ sp,
    const float* __restrict__ petab, float* __restrict__ x, short* __restrict__ xb) {
  __shared__ float px[4][PDc];
  int m0 = blockIdx.x * 4;
  for (int idx = threadIdx.x; idx < 4 * PDc; idx += 256) {
    int tok = idx / PDc, k = idx % PDc;
    int m = m0 + tok;
    int b = m / LLc, l = m % LLc;
    int t = l / KKc;
    int v = pidx[m];
    int np_ = vidx[v];
    int hp = np_ / NWPc, wp = np_ % NWPc;
    int r = k / PSZ, c = k % PSZ;
    px[tok][k] = ximg[(((size_t)b * TT + t) * HH + hp * PSZ + r) * WWI + wp * PSZ + c];
  }
  __syncthreads();
  int d = threadIdx.x;
  float a0 = 0.f, a1 = 0.f, a2 = 0.f, a3 = 0.f;
  const float* wrow = pew + (size_t)d * PDc;
#pragma unroll 4
  for (int k = 0; k < PDc; k++) {
    float w = wrow[k];
    a0 += w * px[0][k]; a1 += w * px[1][k]; a2 += w * px[2][k]; a3 += w * px[3][k];
  }
  float accs[4] = {a0, a1, a2, a3};
#pragma unroll
  for (int tok = 0; tok < 4; tok++) {
    int m = m0 + tok;
    int l = m % LLc; int t = l / KKc;
    int v = pidx[m];
    float val = accs[tok] + peb[d] + sp[(size_t)v * DDc + d] + petab[(size_t)t * DDc + d];
    x[(size_t)m * DDc + d] = val;
    xb[(size_t)m * DDc + d] = f2bf(val);
  }
}

// ---------------- generic bf16 MFMA GEMM: C[m,n] = sum_k A[m,k]*W[n,k] + bias[n] ----------------
#define GM_QKV 0
#define GM_F32 1
#define GM_RELU 2

template <int MODE>
__global__ __launch_bounds__(256) void gemm_bt(
    const short* __restrict__ A, int lda,
    const short* __restrict__ W, int ldw,
    const float* __restrict__ bias,
    void* __restrict__ outp, int N, int K,
    short* __restrict__ vT, float qscale) {
  __shared__ short As[64][40];   // stride 40 bf16 = 80B, 16B-aligned, ~2-4 way conflicts
  __shared__ short Ws[64][40];
  int tid = threadIdx.x;
  int m0 = blockIdx.x * 64;
  int n0 = blockIdx.y * 64;
  int wave = tid >> 6, lane = tid & 63;
  int wr = (wave >> 1) * 32, wc = (wave & 1) * 32;
  int g = lane >> 4, c = lane & 15;
  f32x4 acc[2][2];
#pragma unroll
  for (int i = 0; i < 2; i++)
#pragma unroll
    for (int j = 0; j < 2; j++) { acc[i][j][0] = 0.f; acc[i][j][1] = 0.f; acc[i][j][2] = 0.f; acc[i][j][3] = 0.f; }
  int lrow = tid >> 2, lcg = (tid & 3) * 8;
  const short* aptr = A + (size_t)(m0 + lrow) * lda + lcg;
  const short* wptr = W + (size_t)(n0 + lrow) * ldw + lcg;
  for (int k0 = 0; k0 < K; k0 += 32) {
    *(s16x8*)&As[lrow][lcg] = *(const s16x8*)(aptr + k0);
    *(s16x8*)&Ws[lrow][lcg] = *(const s16x8*)(wptr + k0);
    __syncthreads();
    s16x8 va0 = *(const s16x8*)&As[wr + c][g * 8];
    s16x8 va1 = *(const s16x8*)&As[wr + 16 + c][g * 8];
    s16x8 vb0 = *(const s16x8*)&Ws[wc + c][g * 8];
    s16x8 vb1 = *(const s16x8*)&Ws[wc + 16 + c][g * 8];
    acc[0][0] = __builtin_amdgcn_mfma_f32_16x16x32_bf16(va0, vb0, acc[0][0], 0, 0, 0);
    acc[0][1] = __builtin_amdgcn_mfma_f32_16x16x32_bf16(va0, vb1, acc[0][1], 0, 0, 0);
    acc[1][0] = __builtin_amdgcn_mfma_f32_16x16x32_bf16(va1, vb0, acc[1][0], 0, 0, 0);
    acc[1][1] = __builtin_amdgcn_mfma_f32_16x16x32_bf16(va1, vb1, acc[1][1], 0, 0, 0);
    __syncthreads();
  }
#pragma unroll
  for (int i = 0; i < 2; i++)
#pragma unroll
    for (int j = 0; j < 2; j++) {
      int mbase = m0 + wr + i * 16 + g * 4;
      int n = n0 + wc + j * 16 + c;
      float bv = bias[n];
#pragma unroll
      for (int r = 0; r < 4; r++) {
        int m = mbase + r;
        float val = acc[i][j][r] + bv;
        if (MODE == GM_QKV) {
          int b = m / LLc, l = m % LLc;
          if (n < 512) {
            if (n < 256) val *= qscale;   // fold softmax scale * log2e into q
            ((short*)outp)[((size_t)b * LPc + l) * 768 + n] = f2bf(val);
          } else {
            // v stored transposed: vT[(b*256 + d)*LP + l]
            vT[((size_t)b * DDc + (n - 512)) * LPc + l] = f2bf(val);
          }
        } else if (MODE == GM_F32) {
          ((float*)outp)[(size_t)m * N + n] = val;
        } else {  // GM_RELU -> bf16
          ((short*)outp)[(size_t)m * N + n] = f2bf(val > 0.f ? val : 0.f);
        }
      }
    }
}

// ---------------- flash attention: per-(b,h), 16 q-rows per wave, 32 keys/iter ----------------
__global__ __launch_bounds__(256) void flash_kernel(
    const short* __restrict__ qkv, const short* __restrict__ vT,
    short* __restrict__ attnout) {
  __shared__ short plds[4][16 * 40];   // per-wave P transpose buffer (stride 40 bf16)
  int wave = threadIdx.x >> 6, lane = threadIdx.x & 63;
  int g = lane >> 4, c = lane & 15;
  int bh = blockIdx.y;
  int b = bh >> 3, h = bh & 7;
  int q0 = blockIdx.x * 64 + wave * 16;

  const short* qptr = qkv + ((size_t)b * LPc + q0 + c) * 768 + h * 32 + g * 8;
  s16x8 qfrag = *(const s16x8*)qptr;
  const short* kbase = qkv + (size_t)b * LPc * 768 + 256 + h * 32 + g * 8;
  const short* vbase = vT + ((size_t)b * DDc + h * 32) * LPc;
  short* pw = &plds[wave][0];

  f32x4 o0, o1;
  o0[0]=o0[1]=o0[2]=o0[3]=0.f; o1[0]=o1[1]=o1[2]=o1[3]=0.f;
  float mrun[4] = {-1e30f, -1e30f, -1e30f, -1e30f};
  float lrun[4] = {0.f, 0.f, 0.f, 0.f};
  f32x4 zero4; zero4[0]=zero4[1]=zero4[2]=zero4[3]=0.f;

  for (int kt = 0; kt < 68; kt++) {
    int key0 = kt * 32;
    s16x8 kf0 = *(const s16x8*)(kbase + (size_t)(key0 + c) * 768);
    s16x8 kf1 = *(const s16x8*)(kbase + (size_t)(key0 + 16 + c) * 768);
    f32x4 s0 = __builtin_amdgcn_mfma_f32_16x16x32_bf16(qfrag, kf0, zero4, 0, 0, 0);
    f32x4 s1 = __builtin_amdgcn_mfma_f32_16x16x32_bf16(qfrag, kf1, zero4, 0, 0, 0);
    // mask padded keys by assignment (also kills any NaN from padded garbage)
    if (key0 + c >= LLc)      { s0[0] = s0[1] = s0[2] = s0[3] = -1e30f; }
    if (key0 + 16 + c >= LLc) { s1[0] = s1[1] = s1[2] = s1[3] = -1e30f; }
    float alpha[4];
    f32x4 p0, p1;
#pragma unroll
    for (int i = 0; i < 4; i++) {
      float mx = fmaxf(s0[i], s1[i]);
      mx = fmaxf(mx, __shfl_xor(mx, 1));
      mx = fmaxf(mx, __shfl_xor(mx, 2));
      mx = fmaxf(mx, __shfl_xor(mx, 4));
      mx = fmaxf(mx, __shfl_xor(mx, 8));
      float mnew = fmaxf(mrun[i], mx);
      alpha[i] = exp2f(mrun[i] - mnew);   // log2e already folded into q scale
      p0[i] = exp2f(s0[i] - mnew);
      p1[i] = exp2f(s1[i] - mnew);
      float rs = p0[i] + p1[i];
      rs += __shfl_xor(rs, 1);
      rs += __shfl_xor(rs, 2);
      rs += __shfl_xor(rs, 4);
      rs += __shfl_xor(rs, 8);
      lrun[i] = lrun[i] * alpha[i] + rs;
      mrun[i] = mnew;
    }
    // transpose P (D-layout -> A-frag layout) through LDS, as bf16
#pragma unroll
    for (int i = 0; i < 4; i++) {
      pw[(g * 4 + i) * 40 + c]      = f2bf(p0[i]);
      pw[(g * 4 + i) * 40 + 16 + c] = f2bf(p1[i]);
    }
    asm volatile("s_waitcnt lgkmcnt(0)" ::: "memory");
    s16x8 pa = *(const s16x8*)(pw + c * 40 + g * 8);
    const short* vp = vbase + (size_t)c * LPc + key0 + g * 8;
    s16x8 vf0 = *(const s16x8*)vp;
    s16x8 vf1 = *(const s16x8*)(vp + 16 * LPc);
#pragma unroll
    for (int i = 0; i < 4; i++) { o0[i] *= alpha[i]; o1[i] *= alpha[i]; }
    o0 = __builtin_amdgcn_mfma_f32_16x16x32_bf16(pa, vf0, o0, 0, 0, 0);
    o1 = __builtin_amdgcn_mfma_f32_16x16x32_bf16(pa, vf1, o1, 0, 0, 0);
  }
#pragma unroll
  for (int i = 0; i < 4; i++) {
    int l = q0 + g * 4 + i;
    if (l < LLc) {
      float inv = 1.0f / lrun[i];
      attnout[((size_t)b * LLc + l) * DDc + h * 32 + c]      = f2bf(o0[i] * inv);
      attnout[((size_t)b * LLc + l) * DDc + h * 32 + 16 + c] = f2bf(o1[i] * inv);
    }
  }
}

// ---------------- residual + layernorm (one wave per row of 256) ----------------
__global__ __launch_bounds__(256) void ln_kernel(
    const float* __restrict__ xin, const float* __restrict__ res,
    const float* __restrict__ gs, const float* __restrict__ gb,
    float* __restrict__ xout, short* __restrict__ xbout, int rows) {
  int wid = (blockIdx.x * 256 + threadIdx.x) >> 6;
  int lane = threadIdx.x & 63;
  if (wid >= rows) return;
  int dbase = lane * 4;
  float4 v = *(const float4*)(xin + (size_t)wid * DDc + dbase);
  if (res) {
    float4 r = *(const float4*)(res + (size_t)wid * DDc + dbase);
    v.x += r.x; v.y += r.y; v.z += r.z; v.w += r.w;
  }
  float s = v.x + v.y + v.z + v.w;
#pragma unroll
  for (int d = 1; d < 64; d <<= 1) s += __shfl_xor(s, d);
  float mean = s * (1.0f / 256.0f);
  float dx = v.x - mean, dy = v.y - mean, dz = v.z - mean, dw = v.w - mean;
  float sq = dx * dx + dy * dy + dz * dz + dw * dw;
#pragma unroll
  for (int d = 1; d < 64; d <<= 1) sq += __shfl_xor(sq, d);
  float rstd = rsqrtf(sq * (1.0f / 256.0f) + 1e-5f);
  float4 sg = *(const float4*)(gs + dbase);
  float4 bg = *(const float4*)(gb + dbase);
  float o0 = dx * rstd * sg.x + bg.x;
  float o1 = dy * rstd * sg.y + bg.y;
  float o2 = dz * rstd * sg.z + bg.z;
  float o3 = dw * rstd * sg.w + bg.w;
  float4 ov; ov.x = o0; ov.y = o1; ov.z = o2; ov.w = o3;
  *(float4*)(xout + (size_t)wid * DDc + dbase) = ov;
  if (xbout) {
    s16x4 pb;
    pb[0] = f2bf(o0); pb[1] = f2bf(o1); pb[2] = f2bf(o2); pb[3] = f2bf(o3);
    *(s16x4*)(xbout + (size_t)wid * DDc + dbase) = pb;
  }
}

// ---------------- launch ----------------
extern "C" void kernel_launch(void* const* d_in, const int* in_sizes, int n_in,
                              void* d_out, int out_size, void* d_ws, size_t ws_size,
                              hipStream_t stream) {
  const float* x_img = (const float*)d_in[0];
  const unsigned char* pmask = (const unsigned char*)d_in[1];
  const int* vidx = (const int*)d_in[2];
  const float* pew = (const float*)d_in[3];
  const float* peb = (const float*)d_in[4];
  const float* sp = (const float*)d_in[5];
  const float* Wqkv = (const float*)d_in[6];
  const float* bqkv = (const float*)d_in[7];
  const float* Wo = (const float*)d_in[8];
  const float* bo = (const float*)d_in[9];
  const float* ln1s = (const float*)d_in[10];
  const float* ln1b = (const float*)d_in[11];
  const float* W1 = (const float*)d_in[12];
  const float* b1 = (const float*)d_in[13];
  const float* W2 = (const float*)d_in[14];
  const float* b2 = (const float*)d_in[15];
  const float* ln2s = (const float*)d_in[16];
  const float* ln2b = (const float*)d_in[17];
  const float* nfs = (const float*)d_in[18];
  const float* nfb = (const float*)d_in[19];

  char* ws = (char*)d_ws;
  // workspace layout (all offsets multiples of 256B); total ~116 MB
  size_t o_wq = 0;
  size_t o_wo = o_wq + (size_t)NLc * 768 * DDc * 2;       // 2359296
  size_t o_w1 = o_wo + (size_t)NLc * DDc * DDc * 2;       // +786432
  size_t o_w2 = o_w1 + (size_t)NLc * DFFc * DDc * 2;      // +3145728
  size_t o_pe = o_w2 + (size_t)NLc * DFFc * DDc * 2;      // +3145728
  size_t o_pi = o_pe + (size_t)TT * DDc * 4;              // +92160
  size_t o_x  = o_pi + (size_t)MTOT * 4;                  // +69120
  size_t o_xb = o_x  + (size_t)MTOT * DDc * 4;            // +17694720
  size_t o_qk = o_xb + (size_t)MTOT * DDc * 2;            // +8847360
  size_t o_vt = o_qk + (size_t)BB * LPc * 768 * 2;        // +26738688
  size_t o_at = o_vt + (size_t)BB * DDc * LPc * 2;        // +8912896
  size_t o_h  = o_at + (size_t)MTOT * DDc * 2;            // +8847360
  size_t o_ob = o_qk;  // obuf (f32 GEMM out, 17.7MB) aliases qkv region (free at that point)

  short* wqb = (short*)(ws + o_wq);
  short* wob = (short*)(ws + o_wo);
  short* w1b = (short*)(ws + o_w1);
  short* w2b = (short*)(ws + o_w2);
  float* petab = (float*)(ws + o_pe);
  int* pidx = (int*)(ws + o_pi);
  float* xbuf = (float*)(ws + o_x);
  short* xb = (short*)(ws + o_xb);
  short* qkvb = (short*)(ws + o_qk);
  short* vtb = (short*)(ws + o_vt);
  short* atb = (short*)(ws + o_at);
  short* hb = (short*)(ws + o_h);
  float* obuf = (float*)(ws + o_ob);

  const float qscale = 0.17677669529663687f * 1.4426950408889634f; // 1/sqrt(32) * log2(e)

  // weight conversion
  {
    int n;
    n = NLc * 768 * DDc;  cvt_bf16_kernel<<<(n + 255) / 256, 256, 0, stream>>>(Wqkv, wqb, n);
    n = NLc * DDc * DDc;  cvt_bf16_kernel<<<(n + 255) / 256, 256, 0, stream>>>(Wo, wob, n);
    n = NLc * DFFc * DDc; cvt_bf16_kernel<<<(n + 255) / 256, 256, 0, stream>>>(W1, w1b, n);
    n = NLc * DFFc * DDc; cvt_bf16_kernel<<<(n + 255) / 256, 256, 0, stream>>>(W2, w2b, n);
  }
  pe_kernel<<<(TT * 128 + 255) / 256, 256, 0, stream>>>(petab);
  order_kernel<<<(BB * TT + 3) / 4, 256, 0, stream>>>(pmask, vidx, pidx);
  embed_kernel<<<MTOT / 4, 256, 0, stream>>>(x_img, vidx, pidx, pew, peb, sp, petab, xbuf, xb);

  for (int i = 0; i < NLc; i++) {
    gemm_bt<GM_QKV><<<dim3(MTOT / 64, 768 / 64), 256, 0, stream>>>(
        xb, DDc, wqb + (size_t)i * 768 * DDc, DDc, bqkv + i * 768,
        qkvb, 768, DDc, vtb, qscale);
    flash_kernel<<<dim3((LLc + 63) / 64, BB * NHEADc), 256, 0, stream>>>(qkvb, vtb, atb);
    gemm_bt<GM_F32><<<dim3(MTOT / 64, DDc / 64), 256, 0, stream>>>(
        atb, DDc, wob + (size_t)i * DDc * DDc, DDc, bo + i * DDc,
        obuf, DDc, DDc, nullptr, 0.f);
    ln_kernel<<<MTOT / 4, 256, 0, stream>>>(xbuf, obuf, ln1s + i * DDc, ln1b + i * DDc, xbuf, xb, MTOT);
    gemm_bt<GM_RELU><<<dim3(MTOT / 64, DFFc / 64), 256, 0, stream>>>(
        xb, DDc, w1b + (size_t)i * DFFc * DDc, DDc, b1 + i * DFFc,
        hb, DFFc, DDc, nullptr, 0.f);
    gemm_bt<GM_F32><<<dim3(MTOT / 64, DDc / 64), 256, 0, stream>>>(
        hb, DFFc, w2b + (size_t)i * DFFc * DDc, DFFc, b2 + i * DDc,
        obuf, DDc, DFFc, nullptr, 0.f);
    ln_kernel<<<MTOT / 4, 256, 0, stream>>>(xbuf, obuf, ln2s + i * DDc, ln2b + i * DDc, xbuf, xb, MTOT);
  }
  ln_kernel<<<MTOT / 4, 256, 0, stream>>>(xbuf, nullptr, nfs, nfb, (float*)d_out, nullptr, MTOT);
}